// Round 1
// baseline (205.251 us; speedup 1.0000x reference)
//
#include <hip/hip_runtime.h>
#include <hip/hip_bf16.h>
#include <stdint.h>

#define E_DIM 1280
#define KDIM 588
#define KPAD 608              // W row stride (bf16 elems)
#define ALD  616              // LDS A-tile row stride (+8 pad: 308 words % 32 = 20 -> 2-way banks, free)
#define M_TOTAL 6016
#define EMB_FLOATS (5*2048*1280)

// prep kernel (256 thr): conv_w -> bf16 only
#define PREP_BLOCKS 760       // 1280*608/4/256

// fused gemm kernel (512 thr)
#define GEMM_BLOCKS 188            // 6016/32
#define ZERO_BLOCKS2 660           // 1351680 float4 / 2048
#define MASK_BLOCKS2 2560          // 5242880 float4 / 2048
#define FUSED_BLOCKS (GEMM_BLOCKS + ZERO_BLOCKS2 + MASK_BLOCKS2)

typedef __attribute__((ext_vector_type(8))) short bf16x8;
typedef __attribute__((ext_vector_type(4))) float f32x4;

struct us4 { unsigned short x, y, z, w; };

__device__ __forceinline__ unsigned short f2bf(float f) {
    unsigned int u = __float_as_uint(f);
    u += 0x7fff + ((u >> 16) & 1);
    return (unsigned short)(u >> 16);
}

// ---------------------------------------------------------------------------
// Kernel 1: conv_w -> bf16 (tiny; only true cross-block dependency)
// ---------------------------------------------------------------------------
__global__ __launch_bounds__(256) void prep_w(
    const float* __restrict__ conv_w, us4* __restrict__ W4)
{
    int idx4 = blockIdx.x * 256 + threadIdx.x;
    int e  = idx4 / 152;
    int k4 = (idx4 - e * 152) * 4;
    us4 v = {0, 0, 0, 0};
    if (k4 < KDIM) {
        const float* p = conv_w + (size_t)e * KDIM + k4;
        v.x = f2bf(p[0]); v.y = f2bf(p[1]); v.z = f2bf(p[2]); v.w = f2bf(p[3]);
    }
    W4[idx4] = v;
}

// ---------------------------------------------------------------------------
// Kernel 2 (fused): per-block A-tile extraction (img -> LDS bf16) +
// GEMM(M=32 x N=1280, B frags from L2) + pos-embed bilinear + conv_b +
// LayerNorm + scatter.  Extra blocks do emb-zero and mask fills.
// ---------------------------------------------------------------------------
__global__ __launch_bounds__(512) void fused_gemm(
    const float* __restrict__ i0, const float* __restrict__ i1,
    const float* __restrict__ i2, const float* __restrict__ i3,
    const float* __restrict__ i4, const float* __restrict__ i5,
    const unsigned short* __restrict__ Wb,
    const float* __restrict__ pos_table, const float* __restrict__ conv_b,
    const float* __restrict__ ln_w, const float* __restrict__ ln_b,
    float* __restrict__ out, float4* __restrict__ out4)
{
    const int bid = blockIdx.x;
    const int t = threadIdx.x;

    __shared__ __align__(16) unsigned short Atile[32][ALD];
    __shared__ float part_s[8][32], part_s2[8][32], ln_m[32], ln_i[32];

    if (bid < GEMM_BLOCKS) {
        const int m0   = bid * 32;
        const int wave = t >> 6;
        const int lane = t & 63;
        const int l16  = lane & 15, q = lane >> 4;
        const int ncol0 = wave * 160;

        // ---- block-uniform image geometry (all boundaries divisible by 32)
        int img     = (m0 < 1024) ? 0 : (m0 < 2560) ? 1 : (m0 < 3136) ? 2 : (m0 < 3648) ? 3 : (m0 < 5248) ? 4 : 5;
        int rowOff  = (img == 0) ? 0 : (img == 1) ? 1024 : (img == 2) ? 2560 : (img == 3) ? 3136 : (img == 4) ? 3648 : 5248;
        int h       = (img == 0) ? 32 : (img == 1) ? 32 : (img == 2) ? 24 : (img == 3) ? 16 : (img == 4) ? 40 : 24;
        int w       = (img == 0) ? 32 : (img == 1) ? 48 : (img == 2) ? 24 : (img == 3) ? 32 : (img == 4) ? 40 : 32;
        int outBase = (img == 0) ? 0 : (img == 1) ? 2048 : (img == 2) ? 4096 : (img == 3) ? 4672 : (img == 4) ? 6144 : 8192;
        int IMGW    = (img == 0) ? 448 : (img == 1) ? 672 : (img == 2) ? 336 : (img == 3) ? 448 : (img == 4) ? 560 : 448;
        int PLANE   = (img == 0) ? 200704 : (img == 1) ? 301056 : (img == 2) ? 112896 : (img == 3) ? 100352 : (img == 4) ? 313600 : 150528;
        const float* ip = (img == 0) ? i0 : (img == 1) ? i1 : (img == 2) ? i2 : (img == 3) ? i3 : (img == 4) ? i4 : i5;
        unsigned int magic = (unsigned int)((1u << 22) / (unsigned)w) + 1u;
        float sh = 32.0f / (float)h, sw = 32.0f / (float)w;

        // ---- extract this block's 32 patch-rows straight into LDS (bf16)
        // 32 rows x 152 us4 = 4864 stores, 512 threads -> 9.5 iters
        #pragma unroll
        for (int j = 0; j < 10; ++j) {
            int i = t + j * 512;
            if (j < 9 || i < 4864) {
                int r_local = i / 152;
                int k4 = (i - r_local * 152) * 4;
                us4 v = {0, 0, 0, 0};
                if (k4 < KDIM) {
                    int ri = m0 + r_local - rowOff;
                    unsigned int py = ((unsigned int)ri * magic) >> 22;
                    int px = ri - (int)py * w;
                    int c    = k4 / 196;
                    int rem0 = k4 - c * 196;
                    const float* p = ip + (size_t)c * PLANE + (size_t)((int)py * 14) * IMGW + px * 14;
                    unsigned short o[4];
                    #pragma unroll
                    for (int jj = 0; jj < 4; ++jj) {
                        int rem = rem0 + jj;
                        int iy = rem / 14, ix = rem - iy * 14;
                        o[jj] = f2bf(p[(size_t)iy * IMGW + ix]);
                    }
                    v.x = o[0]; v.y = o[1]; v.z = o[2]; v.w = o[3];
                }
                *(us4*)&Atile[r_local][k4] = v;
            }
        }

        // ---- prefetch first B frags while waiting at the barrier
        const unsigned short* bp = Wb + (size_t)(ncol0 + l16) * KPAD + q * 8;
        bf16x8 bb[2][10];
        #pragma unroll
        for (int ni = 0; ni < 10; ++ni) bb[0][ni] = *(const bf16x8*)(bp + ni * 16 * KPAD);

        __syncthreads();

        // ---- K-loop: A frags from LDS, B register double-buffered from L2
        f32x4 acc[2][10] = {};
        #pragma unroll
        for (int kki = 0; kki < 19; ++kki) {
            const int cur = kki & 1, nxt = cur ^ 1;
            if (kki < 18) {
                const unsigned short* bpn = bp + (kki + 1) * 32;
                #pragma unroll
                for (int ni = 0; ni < 10; ++ni) bb[nxt][ni] = *(const bf16x8*)(bpn + ni * 16 * KPAD);
            }
            bf16x8 a0 = *(const bf16x8*)&Atile[l16][kki * 32 + q * 8];
            bf16x8 a1 = *(const bf16x8*)&Atile[16 + l16][kki * 32 + q * 8];
            #pragma unroll
            for (int ni = 0; ni < 10; ++ni) {
                acc[0][ni] = __builtin_amdgcn_mfma_f32_16x16x32_bf16(a0, bb[cur][ni], acc[0][ni], 0, 0, 0);
                acc[1][ni] = __builtin_amdgcn_mfma_f32_16x16x32_bf16(a1, bb[cur][ni], acc[1][ni], 0, 0, 0);
            }
        }

        // hoist per-column params (10 cols per lane)
        float cbv[10], gv[10], bev[10];
        #pragma unroll
        for (int ni = 0; ni < 10; ++ni) {
            int col = ncol0 + ni * 16 + l16;
            cbv[ni] = conv_b[col];
            gv[ni]  = ln_w[col];
            bev[ni] = ln_b[col];
        }

        // pass 1: add conv_b + pos, per-row stats
        #pragma unroll
        for (int mi = 0; mi < 2; ++mi) {
            #pragma unroll
            for (int reg = 0; reg < 4; ++reg) {
                int row_t = mi * 16 + q * 4 + reg;
                int ri = m0 + row_t - rowOff;
                unsigned int y = ((unsigned int)ri * magic) >> 22;
                int x = ri - (int)y * w;
                float cy = fminf(fmaxf(((float)y + 0.5f) * sh - 0.5f, 0.0f), 31.0f);
                float cx = fminf(fmaxf(((float)x + 0.5f) * sw - 0.5f, 0.0f), 31.0f);
                int y0 = (int)cy; int y1 = min(y0 + 1, 31); float wy = cy - (float)y0;
                int x0 = (int)cx; int x1 = min(x0 + 1, 31); float wx = cx - (float)x0;
                float w00 = (1.f - wy) * (1.f - wx), w01 = (1.f - wy) * wx;
                float w10 = wy * (1.f - wx),         w11 = wy * wx;
                const float* P00 = pos_table + (size_t)(1 + y0*32 + x0) * E_DIM;
                const float* P01 = pos_table + (size_t)(1 + y0*32 + x1) * E_DIM;
                const float* P10 = pos_table + (size_t)(1 + y1*32 + x0) * E_DIM;
                const float* P11 = pos_table + (size_t)(1 + y1*32 + x1) * E_DIM;
                float s = 0.f, s2 = 0.f;
                #pragma unroll
                for (int ni = 0; ni < 10; ++ni) {
                    int col = ncol0 + ni * 16 + l16;
                    float p = w00*P00[col] + w01*P01[col] + w10*P10[col] + w11*P11[col];
                    float v = acc[mi][ni][reg] + cbv[ni] + p;
                    acc[mi][ni][reg] = v;
                    s += v; s2 += v * v;
                }
                #pragma unroll
                for (int msk = 1; msk < 16; msk <<= 1) {
                    s  += __shfl_xor(s,  msk, 64);
                    s2 += __shfl_xor(s2, msk, 64);
                }
                if (l16 == 0) { part_s[wave][row_t] = s; part_s2[wave][row_t] = s2; }
            }
        }
        __syncthreads();
        if (t < 32) {
            float S = 0.f, S2 = 0.f;
            #pragma unroll
            for (int w2 = 0; w2 < 8; ++w2) { S += part_s[w2][t]; S2 += part_s2[w2][t]; }
            float mean = S / 1280.f;
            float var  = S2 / 1280.f - mean * mean;
            ln_m[t] = mean;
            ln_i[t] = 1.f / sqrtf(var + 1e-5f);
        }
        __syncthreads();

        // pass 2: normalize + scatter
        #pragma unroll
        for (int mi = 0; mi < 2; ++mi) {
            #pragma unroll
            for (int reg = 0; reg < 4; ++reg) {
                int row_t = mi * 16 + q * 4 + reg;
                int ri = m0 + row_t - rowOff;
                float mean = ln_m[row_t], inv = ln_i[row_t];
                float* orow = out + (size_t)(outBase + ri) * E_DIM;
                #pragma unroll
                for (int ni = 0; ni < 10; ++ni) {
                    int col = ncol0 + ni * 16 + l16;
                    orow[col] = (acc[mi][ni][reg] - mean) * inv * gv[ni] + bev[ni];
                }
            }
        }
    } else if (bid < GEMM_BLOCKS + ZERO_BLOCKS2) {
        // zero unfilled emb rows: 4224 rows x 320 float4 = 1,351,680 f4
        int base = (bid - GEMM_BLOCKS) * 2048 + t;
        #pragma unroll
        for (int j = 0; j < 4; ++j) {
            int idx = base + j * 512;
            int zrow = idx / 320;
            int c4   = idx - zrow * 320;
            int b, rowInB;
            if      (zrow < 1024) { b = 0; rowInB = 1024 + zrow; }
            else if (zrow < 1536) { b = 1; rowInB = 1536 + (zrow - 1024); }
            else if (zrow < 2496) { b = 2; rowInB = 1088 + (zrow - 1536); }
            else if (zrow < 2944) { b = 3; rowInB = 1600 + (zrow - 2496); }
            else                  { b = 4; rowInB =  768 + (zrow - 2944); }
            size_t o4 = ((size_t)(b * 2048 + rowInB) * E_DIM) / 4 + c4;
            out4[o4] = make_float4(0.f, 0.f, 0.f, 0.f);
        }
    } else {
        // mask fill: 5 x 2048 x 512 float4
        int base = (bid - GEMM_BLOCKS - ZERO_BLOCKS2) * 2048 + t;
        #pragma unroll
        for (int j = 0; j < 4; ++j) {
            int m4 = base + j * 512;
            int b  = m4 >> 20;
            int rr = (m4 >> 9) & 2047;
            int c0 = (m4 & 511) * 4;
            int h0 = (b == 0) ? 1024 : (b == 1) ? 1536 : (b == 2) ? 576 : (b == 3) ? 1600 : 768;
            bool on = (rr < h0 && c0 < h0);
            if (b == 2) on = on || (rr >= 576 && rr < 1088 && c0 >= 576 && c0 < 1088);
            float f = on ? 1.f : 0.f;
            out4[(size_t)(EMB_FLOATS / 4) + m4] = make_float4(f, f, f, f);
        }
    }
}

// ---------------------------------------------------------------------------
extern "C" void kernel_launch(void* const* d_in, const int* in_sizes, int n_in,
                              void* d_out, int out_size, void* d_ws, size_t ws_size,
                              hipStream_t stream) {
    const float* img0 = (const float*)d_in[0];
    const float* img1 = (const float*)d_in[1];
    const float* img2 = (const float*)d_in[2];
    const float* img3 = (const float*)d_in[3];
    const float* img4 = (const float*)d_in[4];
    const float* img5 = (const float*)d_in[5];
    const float* conv_w    = (const float*)d_in[6];
    const float* conv_b    = (const float*)d_in[7];
    const float* pos_table = (const float*)d_in[8];
    const float* ln_w      = (const float*)d_in[9];
    const float* ln_b      = (const float*)d_in[10];
    float* out = (float*)d_out;

    unsigned short* Wbf = (unsigned short*)d_ws;   // 1.56 MB bf16 W

    prep_w<<<PREP_BLOCKS, 256, 0, stream>>>(conv_w, (us4*)Wbf);

    fused_gemm<<<FUSED_BLOCKS, 512, 0, stream>>>(
        img0, img1, img2, img3, img4, img5,
        Wbf, pos_table, conv_b, ln_w, ln_b, out, (float4*)out);
}